// Round 6
// baseline (298.916 us; speedup 1.0000x reference)
//
#include <hip/hip_runtime.h>
#include <math.h>

#define BB 2
#define CC 512
#define NN 4096          // H*W
#define NH 8
#define HD 64
#define NG 32
#define CPG 16           // C / NUM_GROUPS

typedef __attribute__((ext_vector_type(8))) short short8;
typedef __attribute__((ext_vector_type(4))) float f32x4;
typedef __attribute__((ext_vector_type(16))) float f32x16;
typedef __attribute__((ext_vector_type(2))) unsigned int u32x2;

typedef __attribute__((address_space(1))) void glb_t;
typedef __attribute__((address_space(3))) void lds_t;

__device__ __forceinline__ void async16(const void* g, void* l) {
  // global -> LDS direct, 16B per lane; LDS dest = wave-uniform base + lane*16
  __builtin_amdgcn_global_load_lds((const glb_t*)g, (lds_t*)l, 16, 0, 0);
}

__device__ __forceinline__ unsigned short f2bf(float f) {
  unsigned int u = __float_as_uint(f);
  u += 0x7fffu + ((u >> 16) & 1u);   // RNE
  return (unsigned short)(u >> 16);
}

__device__ __forceinline__ unsigned int cvt_pk_bf16(float a, float b) {
  unsigned int r;
  asm("v_cvt_pk_bf16_f32 %0, %1, %2" : "=v"(r) : "v"(a), "v"(b));
  return r;   // lo = bf16(a), hi = bf16(b)
}

// ---------------- K1: GroupNorm stats (mean, rstd) per (b, g) ----------------
__global__ __launch_bounds__(256) void k_gnstats(const float* __restrict__ x,
                                                 float* __restrict__ stats) {
  int b = blockIdx.x >> 5, g = blockIdx.x & 31;
  const float4* p = (const float4*)(x + (size_t)(b * CC + g * CPG) * NN);
  double s = 0.0, sq = 0.0;
  for (int i = threadIdx.x; i < (CPG * NN) / 4; i += 256) {
    float4 v = p[i];
    s  += (double)v.x + (double)v.y + (double)v.z + (double)v.w;
    sq += (double)v.x * v.x + (double)v.y * v.y + (double)v.z * v.z + (double)v.w * v.w;
  }
  __shared__ double red[512];
  red[threadIdx.x] = s; red[256 + threadIdx.x] = sq;
  __syncthreads();
  for (int off = 128; off > 0; off >>= 1) {
    if (threadIdx.x < off) {
      red[threadIdx.x] += red[threadIdx.x + off];
      red[256 + threadIdx.x] += red[256 + threadIdx.x + off];
    }
    __syncthreads();
  }
  if (threadIdx.x == 0) {
    double mean = red[0] / (double)(CPG * NN);
    double var  = red[256] / (double)(CPG * NN) - mean * mean;
    stats[(b * NG + g) * 2]     = (float)mean;
    stats[(b * NG + g) * 2 + 1] = (float)(1.0 / sqrt(var + 1e-5));
  }
}

// ------- K2: GN apply + transpose [B,C,N] -> hT[B*N][C] bf16 (LDS tiled) -----
__global__ __launch_bounds__(256) void k_gnapply(const float* __restrict__ x,
                                                 const float* __restrict__ gw,
                                                 const float* __restrict__ gb,
                                                 const float* __restrict__ stats,
                                                 unsigned short* __restrict__ hT) {
  int bid = blockIdx.x;
  int b = bid >> 9;
  int c0 = ((bid >> 6) & 7) * 64;
  int n0 = (bid & 63) * 64;
  __shared__ float tile[64 * 65];
  int t = threadIdx.x;
#pragma unroll
  for (int i = 0; i < 16; ++i) {
    int e = i * 256 + t, c = e >> 6, n = e & 63;
    int cg = c0 + c, g = cg >> 4;
    float mu = stats[(b * NG + g) * 2], rs = stats[(b * NG + g) * 2 + 1];
    float v = x[(size_t)(b * CC + cg) * NN + n0 + n];
    tile[c * 65 + n] = (v - mu) * rs * gw[cg] + gb[cg];
  }
  __syncthreads();
#pragma unroll
  for (int i = 0; i < 16; ++i) {
    int e = i * 256 + t, n = e >> 6, c = e & 63;
    hT[(size_t)(b * NN + n0 + n) * CC + c0 + c] = f2bf(tile[c * 65 + n]);
  }
}

// ---------------- K3: f32 -> bf16 convert (weights) ----------------
__global__ __launch_bounds__(256) void k_cvt(const float* __restrict__ src,
                                             unsigned short* __restrict__ dst) {
  int i = (blockIdx.x * 256 + threadIdx.x) * 4;
  float4 v = *(const float4*)(src + i);
  ushort4 o;
  o.x = f2bf(v.x); o.y = f2bf(v.y); o.z = f2bf(v.z); o.w = f2bf(v.w);
  *(ushort4*)(dst + i) = o;
}

// ------- shared GEMM mainloop: 128x128 tile, K=512 fixed, A[ld=512], B[N][512]
__device__ __forceinline__ void gemm_mainloop(const unsigned short* __restrict__ A,
                                              const unsigned short* __restrict__ Bm,
                                              char* smem, int m0, int n0,
                                              f32x4 acc[4][4]) {
  const int t = threadIdx.x, wave = t >> 6, lane = t & 63;
  const int l15 = lane & 15, lhi = lane >> 4;
  const int wr = wave >> 1, wc = wave & 1;
  const f32x4 fz = {0.f, 0.f, 0.f, 0.f};
#pragma unroll
  for (int mi = 0; mi < 4; ++mi)
#pragma unroll
    for (int ni = 0; ni < 4; ++ni) acc[mi][ni] = fz;

  for (int kt = 0; kt < 8; ++kt) {
    __syncthreads();   // previous iter's ds_reads done
#pragma unroll
    for (int issue = 0; issue < 4; ++issue) {
      int slot = issue * 256 + t;
      int row = slot >> 3, g = slot & 7;
      async16(A + (size_t)(m0 + row) * 512 + kt * 64 + g * 8,
              smem + issue * 4096 + wave * 1024);
      async16(Bm + (size_t)(n0 + row) * 512 + kt * 64 + g * 8,
              smem + 16384 + issue * 4096 + wave * 1024);
    }
    __syncthreads();   // drains vmcnt -> tiles ready
#pragma unroll
    for (int kk = 0; kk < 2; ++kk) {
      short8 a[4], bf[4];
#pragma unroll
      for (int mi = 0; mi < 4; ++mi)
        a[mi] = *(const short8*)(smem + (wr * 64 + mi * 16 + l15) * 128 + kk * 64 + lhi * 16);
#pragma unroll
      for (int ni = 0; ni < 4; ++ni)
        bf[ni] = *(const short8*)(smem + 16384 + (wc * 64 + ni * 16 + l15) * 128 + kk * 64 + lhi * 16);
#pragma unroll
      for (int mi = 0; mi < 4; ++mi)
#pragma unroll
        for (int ni = 0; ni < 4; ++ni)
          acc[mi][ni] = __builtin_amdgcn_mfma_f32_16x16x32_bf16(a[mi], bf[ni], acc[mi][ni], 0, 0, 0);
    }
  }
}

// ---------------- K4: QKV GEMM  [8192,512]x[1536,512]^T -> qkv bf16 ----------
__global__ __launch_bounds__(256) void k_qkvgemm(const unsigned short* __restrict__ hT,
                                                 const unsigned short* __restrict__ Wq,
                                                 unsigned short* __restrict__ qkv) {
  __shared__ char smem[32768];
  f32x4 acc[4][4];
  int m0 = blockIdx.x * 128, n0 = blockIdx.y * 128;
  gemm_mainloop(hT, Wq, smem, m0, n0, acc);
  const int t = threadIdx.x, wave = t >> 6, lane = t & 63;
  const int l15 = lane & 15, lhi = lane >> 4;
  const int wr = wave >> 1, wc = wave & 1;
#pragma unroll
  for (int mi = 0; mi < 4; ++mi)
#pragma unroll
    for (int ni = 0; ni < 4; ++ni)
#pragma unroll
      for (int r = 0; r < 4; ++r) {
        int m = m0 + wr * 64 + mi * 16 + lhi * 4 + r;
        int o = n0 + wc * 64 + ni * 16 + l15;
        qkv[(size_t)m * 1536 + o] = f2bf(acc[mi][ni][r]);
      }
}

// ---------------- K5: V transpose -> vT[bh][d][n] bf16 ----------------
__global__ __launch_bounds__(256) void k_vtrans(const unsigned short* __restrict__ qkv,
                                                unsigned short* __restrict__ vT) {
  int bid = blockIdx.x;
  int bh = bid >> 6, n0 = (bid & 63) * 64;
  int b = bh >> 3, h = bh & 7;
  __shared__ unsigned short tile[64 * 65];
  int t = threadIdx.x;
#pragma unroll
  for (int i = 0; i < 16; ++i) {
    int e = i * 256 + t, n = e >> 6, d = e & 63;
    tile[d * 65 + n] = qkv[(size_t)(b * NN + n0 + n) * 1536 + 1024 + h * 64 + d];
  }
  __syncthreads();
#pragma unroll
  for (int i = 0; i < 16; ++i) {
    int e = i * 256 + t, d = e >> 6, n = e & 63;
    vT[(size_t)(bh * 64 + d) * NN + n0 + n] = tile[d * 65 + n];
  }
}

// ---------------- K6: flash attention v4 (split-k waves, plane-major LDS) ----
// 4 waves/block: wq = q-group (32 rows), wk = k-half (32 of KVBLK=64).
// LDS per buffer (16KB): K planes [wk][kk][lh][r31] @0, V planes [kcg][dt][lh][r31] @8K.
// Every ds_read_b128 = 64 lanes reading contiguous 1024B (conflict-free by construction).
// No max tracking (logits bounded); P redistributed in-register (cvt_pk+permlane32_swap).
// Cross-k-half O/l reduction once at the end via LDS.
__global__ __launch_bounds__(256) void k_attn(const unsigned short* __restrict__ qkv,
                                              const unsigned short* __restrict__ vT,
                                              unsigned short* __restrict__ att) {
  __shared__ char smem[32768];   // buf0 @0, buf1 @16384
  const int t = threadIdx.x, wave = t >> 6, lane = t & 63;
  const int l31 = lane & 31, lh = lane >> 5;
  const int wq = wave >> 1, wk = wave & 1;
  int bid0 = blockIdx.x;
  int bid = (bid0 & 7) * 128 + (bid0 >> 3);   // XCD swizzle (bijective: 1024 = 8*128)
  int bh = bid >> 6, q0 = (bid & 63) * 64;
  int b = bh >> 3, h = bh & 7;
  const float C = 0.125f * 1.4426950408889634f;   // scale * log2(e)

  // DMA source pointers (per-lane). Plane p = i*4+wave.
  // K: row kv + i*32 + l31, granule wave*2+lh  (plane = [wk=i][kk=wave])
  // V: row (wave&1)*32 + l31, n-granule (i*2 + (wave>>1))*2 + lh (plane = [kcg][dt=wave&1])
  const unsigned short* kS[2];
  const unsigned short* vS[2];
#pragma unroll
  for (int i = 0; i < 2; ++i) {
    kS[i] = qkv + (size_t)(b * NN + i * 32 + l31) * 1536 + 512 + h * 64 + (wave * 2 + lh) * 8;
    vS[i] = vT + (size_t)(bh * 64 + (wave & 1) * 32 + l31) * NN + ((i * 2 + (wave >> 1)) * 2 + lh) * 8;
  }

  // prologue: stage Q -> buf1 K-region (transient), K0/V0 -> buf0
#pragma unroll
  for (int i = 0; i < 2; ++i) {
    async16(qkv + (size_t)(b * NN + q0 + i * 32 + l31) * 1536 + h * 64 + (wave * 2 + lh) * 8,
            smem + 16384 + (i * 4 + wave) * 1024);
    async16(kS[i], smem + (i * 4 + wave) * 1024);
    async16(vS[i], smem + 8192 + (i * 4 + wave) * 1024);
    kS[i] += 98304;   // next kv-tile (64 rows * 1536)
    vS[i] += 64;      // next 64 n
  }

  const int rbK = wk * 4096 + lh * 512 + l31 * 16;
  const int rbV = 8192 + wk * 4096 + lh * 512 + l31 * 16;
  const int rbQ = 16384 + wq * 4096 + lh * 512 + l31 * 16;

  __syncthreads();
  short8 qa[4];
#pragma unroll
  for (int kk = 0; kk < 4; ++kk)
    qa[kk] = *(const short8*)(smem + rbQ + kk * 1024);
  __syncthreads();   // Q reads done before iter0 overwrites buf1

  f32x16 o0 = (f32x16)0.f, o1 = (f32x16)0.f;
  float lsum = 0.f;

#define ATTN_BODY(CURB, NXTB)                                                          \
  {                                                                                    \
    _Pragma("unroll")                                                                  \
    for (int i = 0; i < 2; ++i) {                                                      \
      async16(kS[i], smem + (NXTB) + (i * 4 + wave) * 1024);                           \
      async16(vS[i], smem + (NXTB) + 8192 + (i * 4 + wave) * 1024);                    \
      kS[i] += 98304; vS[i] += 64;                                                     \
    }                                                                                  \
    f32x16 sT = (f32x16)0.f;                                                           \
    __builtin_amdgcn_s_setprio(1);                                                     \
    _Pragma("unroll")                                                                  \
    for (int kk = 0; kk < 4; ++kk) {                                                   \
      short8 ka = *(const short8*)(smem + (CURB) + rbK + kk * 1024);                   \
      sT = __builtin_amdgcn_mfma_f32_32x32x16_bf16(ka, qa[kk], sT, 0, 0, 0);           \
    }                                                                                  \
    __builtin_amdgcn_s_setprio(0);                                                     \
    float ls0 = 0.f, ls1 = 0.f;                                                        \
    _Pragma("unroll")                                                                  \
    for (int r = 0; r < 16; r += 2) {                                                  \
      sT[r]     = __builtin_amdgcn_exp2f(sT[r] * C);                                   \
      sT[r + 1] = __builtin_amdgcn_exp2f(sT[r + 1] * C);                               \
      ls0 += sT[r]; ls1 += sT[r + 1];                                                  \
    }                                                                                  \
    lsum += ls0 + ls1;                                                                 \
    __builtin_amdgcn_s_setprio(1);                                                     \
    _Pragma("unroll")                                                                  \
    for (int kc = 0; kc < 2; ++kc) {                                                   \
      int rb = kc * 8;                                                                 \
      unsigned int x0 = cvt_pk_bf16(sT[rb],     sT[rb + 1]);                           \
      unsigned int x1 = cvt_pk_bf16(sT[rb + 2], sT[rb + 3]);                           \
      unsigned int x2 = cvt_pk_bf16(sT[rb + 4], sT[rb + 5]);                           \
      unsigned int x3 = cvt_pk_bf16(sT[rb + 6], sT[rb + 7]);                           \
      unsigned int u0 = x0, u1 = x1, u2 = x2, u3 = x3;                                 \
      asm("v_permlane32_swap_b32 %0, %1" : "+v"(x0), "+v"(u0));                        \
      asm("v_permlane32_swap_b32 %0, %1" : "+v"(x1), "+v"(u1));                        \
      asm("v_permlane32_swap_b32 %0, %1" : "+v"(x2), "+v"(u2));                        \
      asm("v_permlane32_swap_b32 %0, %1" : "+v"(x3), "+v"(u3));                        \
      union { unsigned int d[4]; short8 s; } pb;                                       \
      pb.d[0] = lh ? x2 : x0;                                                          \
      pb.d[1] = lh ? x3 : x1;                                                          \
      pb.d[2] = lh ? u2 : u0;                                                          \
      pb.d[3] = lh ? u3 : u1;                                                          \
      short8 va0 = *(const short8*)(smem + (CURB) + rbV + kc * 2048);                  \
      o0 = __builtin_amdgcn_mfma_f32_32x32x16_bf16(va0, pb.s, o0, 0, 0, 0);            \
      short8 va1 = *(const short8*)(smem + (CURB) + rbV + kc * 2048 + 1024);           \
      o1 = __builtin_amdgcn_mfma_f32_32x32x16_bf16(va1, pb.s, o1, 0, 0, 0);            \
    }                                                                                  \
    __builtin_amdgcn_s_setprio(0);                                                     \
    __syncthreads();                                                                   \
  }

  // 64 kv-tiles; last staged tile (kv=4096) is OOB-into-workspace garbage, never read.
  for (int it2 = 0; it2 < 32; ++it2) {
    ATTN_BODY(0, 16384)
    ATTN_BODY(16384, 0)
  }
#undef ATTN_BODY

  // ---- cross-k-half reduce + store ----
  lsum += __shfl_xor(lsum, 32, 64);
  if (wk) {
    char* os = smem + wq * 8192;
#pragma unroll
    for (int dt = 0; dt < 2; ++dt)
#pragma unroll
      for (int rp = 0; rp < 4; ++rp) {
        f32x4 v;
        v[0] = (dt ? o1 : o0)[4 * rp];     v[1] = (dt ? o1 : o0)[4 * rp + 1];
        v[2] = (dt ? o1 : o0)[4 * rp + 2]; v[3] = (dt ? o1 : o0)[4 * rp + 3];
        *(f32x4*)(os + (dt * 4 + rp) * 1024 + lane * 16) = v;
      }
    *(float*)(smem + 16384 + wq * 256 + lane * 4) = lsum;
  }
  __syncthreads();
  if (!wk) {
    float lt = lsum + *(const float*)(smem + 16384 + wq * 256 + lane * 4);
    float rl = 1.f / lt;
    const char* os = smem + wq * 8192;
#pragma unroll
    for (int dt = 0; dt < 2; ++dt)
#pragma unroll
      for (int rp = 0; rp < 4; ++rp) {
        f32x4 v = *(const f32x4*)(os + (dt * 4 + rp) * 1024 + lane * 16);
        if (dt) {
          o1[4 * rp] += v[0]; o1[4 * rp + 1] += v[1];
          o1[4 * rp + 2] += v[2]; o1[4 * rp + 3] += v[3];
        } else {
          o0[4 * rp] += v[0]; o0[4 * rp + 1] += v[1];
          o0[4 * rp + 2] += v[2]; o0[4 * rp + 3] += v[3];
        }
      }
    unsigned short* abase = att + (size_t)(b * NN + q0 + wq * 32 + l31) * CC + h * 64 + 4 * lh;
#pragma unroll
    for (int dt = 0; dt < 2; ++dt)
#pragma unroll
      for (int rp = 0; rp < 8; ++rp) {
        float e0 = (dt ? o1 : o0)[2 * rp], e1 = (dt ? o1 : o0)[2 * rp + 1];
        unsigned int w = cvt_pk_bf16(e0 * rl, e1 * rl);
        *(unsigned int*)(abase + 32 * dt + 8 * (rp >> 1) + 2 * (rp & 1)) = w;
      }
  }
}

// -------- K7: proj GEMM + fused transpose + bias + residual -> d_out --------
__global__ __launch_bounds__(256) void k_projgemm(const unsigned short* __restrict__ att,
                                                  const unsigned short* __restrict__ Wp,
                                                  const float* __restrict__ x,
                                                  const float* __restrict__ bproj,
                                                  float* __restrict__ out) {
  __shared__ char smem[33280];   // 32768 for GEMM tiles; 4*8320 for epilogue staging
  f32x4 acc[4][4];
  int m0 = blockIdx.x * 128, n0 = blockIdx.y * 128;
  gemm_mainloop(att, Wp, smem, m0, n0, acc);
  const int t = threadIdx.x, wave = t >> 6, lane = t & 63;
  const int l15 = lane & 15, lhi = lane >> 4;
  const int wr = wave >> 1, wc = wave & 1;
  __syncthreads();   // all waves done with GEMM tiles
  float* stg = (float*)(smem + wave * 8320);   // per-wave private 32x65 f32
  int b = m0 >> 12;                            // 4096 pixels per batch
  int nbase = (m0 & 4095) + wr * 64;
#pragma unroll
  for (int half = 0; half < 2; ++half) {
#pragma unroll
    for (int nl = 0; nl < 2; ++nl) {
      int ni = half * 2 + nl;
#pragma unroll
      for (int mi = 0; mi < 4; ++mi)
#pragma unroll
        for (int r = 0; r < 4; ++r) {
          int cl = nl * 16 + l15;
          int row = mi * 16 + lhi * 4 + r;
          stg[cl * 65 + row] = acc[mi][ni][r];  // transposed stage
        }
    }
#pragma unroll 4
    for (int i = 0; i < 32; ++i) {
      int oc = n0 + wc * 64 + half * 32 + i;
      float v = stg[i * 65 + lane];
      size_t idx = (size_t)(b * CC + oc) * NN + nbase + lane;
      out[idx] = x[idx] + v + bproj[oc];
    }
    __syncthreads();
  }
}

// ---------------- launch ----------------
extern "C" void kernel_launch(void* const* d_in, const int* in_sizes, int n_in,
                              void* d_out, int out_size, void* d_ws, size_t ws_size,
                              hipStream_t stream) {
  const float* x     = (const float*)d_in[0];
  const float* gw    = (const float*)d_in[1];
  const float* gb    = (const float*)d_in[2];
  const float* wqkv  = (const float*)d_in[3];
  const float* wproj = (const float*)d_in[4];
  const float* bproj = (const float*)d_in[5];
  float* out = (float*)d_out;
  char* ws = (char*)d_ws;

  // workspace layout (bytes)
  unsigned short* qkvb  = (unsigned short*)(ws + 0);          // 8192*1536*2 = 25165824
  unsigned short* vTb   = (unsigned short*)(ws + 25165824);   // 16*64*4096*2 = 8388608
  unsigned short* attb  = (unsigned short*)(ws + 33554432);   // 8192*512*2  = 8388608
  unsigned short* hTb   = (unsigned short*)(ws + 41943040);   // 8192*512*2  = 8388608
  unsigned short* wqkvb = (unsigned short*)(ws + 50331648);   // 1536*512*2  = 1572864
  unsigned short* wprojb= (unsigned short*)(ws + 51904512);   // 512*512*2   = 524288
  float*          stats = (float*)(ws + 52428800);            // 64*2*4

  k_gnstats<<<64, 256, 0, stream>>>(x, stats);
  k_gnapply<<<1024, 256, 0, stream>>>(x, gw, gb, stats, hTb);
  k_cvt<<<768, 256, 0, stream>>>(wqkv, wqkvb);    // 3*512*512 / 1024
  k_cvt<<<256, 256, 0, stream>>>(wproj, wprojb);  // 512*512 / 1024
  k_qkvgemm<<<dim3(64, 12), 256, 0, stream>>>(hTb, wqkvb, qkvb);
  k_vtrans<<<1024, 256, 0, stream>>>(qkvb, vTb);
  k_attn<<<1024, 256, 0, stream>>>(qkvb, vTb, attb);
  k_projgemm<<<dim3(64, 4), 256, 0, stream>>>(attb, wprojb, x, bproj, out);
}

// Round 7
// 261.185 us; speedup vs baseline: 1.1445x; 1.1445x over previous
//
#include <hip/hip_runtime.h>
#include <math.h>

#define BB 2
#define CC 512
#define NN 4096          // H*W
#define NH 8
#define HD 64
#define NG 32
#define CPG 16           // C / NUM_GROUPS

typedef __attribute__((ext_vector_type(8))) short short8;
typedef __attribute__((ext_vector_type(4))) float f32x4;
typedef __attribute__((ext_vector_type(16))) float f32x16;
typedef __attribute__((ext_vector_type(2))) unsigned int u32x2;

typedef __attribute__((address_space(1))) void glb_t;
typedef __attribute__((address_space(3))) void lds_t;

__device__ __forceinline__ void async16(const void* g, void* l) {
  // global -> LDS direct, 16B per lane; LDS dest = wave-uniform base + lane*16
  __builtin_amdgcn_global_load_lds((const glb_t*)g, (lds_t*)l, 16, 0, 0);
}

__device__ __forceinline__ unsigned short f2bf(float f) {
  unsigned int u = __float_as_uint(f);
  u += 0x7fffu + ((u >> 16) & 1u);   // RNE
  return (unsigned short)(u >> 16);
}

__device__ __forceinline__ unsigned int cvt_pk_bf16(float a, float b) {
  unsigned int r;
  asm("v_cvt_pk_bf16_f32 %0, %1, %2" : "=v"(r) : "v"(a), "v"(b));
  return r;   // lo = bf16(a), hi = bf16(b)
}

// ---------------- K1: GroupNorm stats (mean, rstd) per (b, g) ----------------
__global__ __launch_bounds__(256) void k_gnstats(const float* __restrict__ x,
                                                 float* __restrict__ stats) {
  int b = blockIdx.x >> 5, g = blockIdx.x & 31;
  const float4* p = (const float4*)(x + (size_t)(b * CC + g * CPG) * NN);
  double s = 0.0, sq = 0.0;
  for (int i = threadIdx.x; i < (CPG * NN) / 4; i += 256) {
    float4 v = p[i];
    s  += (double)v.x + (double)v.y + (double)v.z + (double)v.w;
    sq += (double)v.x * v.x + (double)v.y * v.y + (double)v.z * v.z + (double)v.w * v.w;
  }
  __shared__ double red[512];
  red[threadIdx.x] = s; red[256 + threadIdx.x] = sq;
  __syncthreads();
  for (int off = 128; off > 0; off >>= 1) {
    if (threadIdx.x < off) {
      red[threadIdx.x] += red[threadIdx.x + off];
      red[256 + threadIdx.x] += red[256 + threadIdx.x + off];
    }
    __syncthreads();
  }
  if (threadIdx.x == 0) {
    double mean = red[0] / (double)(CPG * NN);
    double var  = red[256] / (double)(CPG * NN) - mean * mean;
    stats[(b * NG + g) * 2]     = (float)mean;
    stats[(b * NG + g) * 2 + 1] = (float)(1.0 / sqrt(var + 1e-5));
  }
}

// ------- K2: GN apply + transpose [B,C,N] -> hT[B*N][C] bf16 (LDS tiled) -----
__global__ __launch_bounds__(256) void k_gnapply(const float* __restrict__ x,
                                                 const float* __restrict__ gw,
                                                 const float* __restrict__ gb,
                                                 const float* __restrict__ stats,
                                                 unsigned short* __restrict__ hT) {
  int bid = blockIdx.x;
  int b = bid >> 9;
  int c0 = ((bid >> 6) & 7) * 64;
  int n0 = (bid & 63) * 64;
  __shared__ float tile[64 * 65];
  int t = threadIdx.x;
#pragma unroll
  for (int i = 0; i < 16; ++i) {
    int e = i * 256 + t, c = e >> 6, n = e & 63;
    int cg = c0 + c, g = cg >> 4;
    float mu = stats[(b * NG + g) * 2], rs = stats[(b * NG + g) * 2 + 1];
    float v = x[(size_t)(b * CC + cg) * NN + n0 + n];
    tile[c * 65 + n] = (v - mu) * rs * gw[cg] + gb[cg];
  }
  __syncthreads();
#pragma unroll
  for (int i = 0; i < 16; ++i) {
    int e = i * 256 + t, n = e >> 6, c = e & 63;
    hT[(size_t)(b * NN + n0 + n) * CC + c0 + c] = f2bf(tile[c * 65 + n]);
  }
}

// ---------------- K3: f32 -> bf16 convert (weights) ----------------
__global__ __launch_bounds__(256) void k_cvt(const float* __restrict__ src,
                                             unsigned short* __restrict__ dst) {
  int i = (blockIdx.x * 256 + threadIdx.x) * 4;
  float4 v = *(const float4*)(src + i);
  ushort4 o;
  o.x = f2bf(v.x); o.y = f2bf(v.y); o.z = f2bf(v.z); o.w = f2bf(v.w);
  *(ushort4*)(dst + i) = o;
}

// ------- shared GEMM mainloop: 128x128 tile, K=512 fixed, A[ld=512], B[N][512]
__device__ __forceinline__ void gemm_mainloop(const unsigned short* __restrict__ A,
                                              const unsigned short* __restrict__ Bm,
                                              char* smem, int m0, int n0,
                                              f32x4 acc[4][4]) {
  const int t = threadIdx.x, wave = t >> 6, lane = t & 63;
  const int l15 = lane & 15, lhi = lane >> 4;
  const int wr = wave >> 1, wc = wave & 1;
  const f32x4 fz = {0.f, 0.f, 0.f, 0.f};
#pragma unroll
  for (int mi = 0; mi < 4; ++mi)
#pragma unroll
    for (int ni = 0; ni < 4; ++ni) acc[mi][ni] = fz;

  for (int kt = 0; kt < 8; ++kt) {
    __syncthreads();   // previous iter's ds_reads done
#pragma unroll
    for (int issue = 0; issue < 4; ++issue) {
      int slot = issue * 256 + t;
      int row = slot >> 3, g = slot & 7;
      async16(A + (size_t)(m0 + row) * 512 + kt * 64 + g * 8,
              smem + issue * 4096 + wave * 1024);
      async16(Bm + (size_t)(n0 + row) * 512 + kt * 64 + g * 8,
              smem + 16384 + issue * 4096 + wave * 1024);
    }
    __syncthreads();   // drains vmcnt -> tiles ready
#pragma unroll
    for (int kk = 0; kk < 2; ++kk) {
      short8 a[4], bf[4];
#pragma unroll
      for (int mi = 0; mi < 4; ++mi)
        a[mi] = *(const short8*)(smem + (wr * 64 + mi * 16 + l15) * 128 + kk * 64 + lhi * 16);
#pragma unroll
      for (int ni = 0; ni < 4; ++ni)
        bf[ni] = *(const short8*)(smem + 16384 + (wc * 64 + ni * 16 + l15) * 128 + kk * 64 + lhi * 16);
#pragma unroll
      for (int mi = 0; mi < 4; ++mi)
#pragma unroll
        for (int ni = 0; ni < 4; ++ni)
          acc[mi][ni] = __builtin_amdgcn_mfma_f32_16x16x32_bf16(a[mi], bf[ni], acc[mi][ni], 0, 0, 0);
    }
  }
}

// ---- K4: QKV GEMM; epilogue writes Q/K plane-major (Qp/Kp), V row-major -----
// Plane layout (per bh, per 64-pixel tile, 8 planes of 1KB):
//   Q/K plane p = blk*4+kk; slot lane l (=lh*32+l31), oct:
//     element [pixel = tile*64 + blk*32 + l31][c = kk*16 + lh*8 + oct]
__global__ __launch_bounds__(256) void k_qkvgemm(const unsigned short* __restrict__ hT,
                                                 const unsigned short* __restrict__ Wq,
                                                 unsigned short* __restrict__ Qp,
                                                 unsigned short* __restrict__ Kp,
                                                 unsigned short* __restrict__ vRM) {
  __shared__ char smem[32768];
  f32x4 acc[4][4];
  int m0 = blockIdx.x * 128, n0 = blockIdx.y * 128;
  gemm_mainloop(hT, Wq, smem, m0, n0, acc);
  const int t = threadIdx.x, wave = t >> 6, lane = t & 63;
  const int l15 = lane & 15, lhi = lane >> 4;
  const int wr = wave >> 1, wc = wave & 1;
#pragma unroll
  for (int mi = 0; mi < 4; ++mi)
#pragma unroll
    for (int ni = 0; ni < 4; ++ni)
#pragma unroll
      for (int r = 0; r < 4; ++r) {
        int m = m0 + wr * 64 + mi * 16 + lhi * 4 + r;
        int o = n0 + wc * 64 + ni * 16 + l15;
        unsigned short bf = f2bf(acc[mi][ni][r]);
        int bb = m >> 12, n = m & 4095;
        int h = (o >> 6) & 7, c = o & 63;
        int bh = bb * 8 + h;
        if (o >= 1024) {
          vRM[((size_t)bh * 4096 + n) * 64 + c] = bf;
        } else {
          int tt2 = n >> 6, blk = (n >> 5) & 1, l31 = n & 31;
          int kk = c >> 4, lh2 = (c >> 3) & 1, oct = c & 7;
          unsigned short* base = (o < 512) ? Qp : Kp;
          base[((((size_t)bh * 64 + tt2) * 8 + blk * 4 + kk) << 9) + lh2 * 256 + l31 * 8 + oct] = bf;
        }
      }
}

// ---- K5: V transpose -> Vp plane-major --------------------------------------
// Vp plane p = wk*4 + kc*2 + dt; slot lane l, oct:
//   element V^T[d = dt*32 + (l&31)][k = tile*64 + wk*32 + kc*16 + (l>>5)*8 + oct]
__global__ __launch_bounds__(256) void k_vtransP(const unsigned short* __restrict__ vRM,
                                                 unsigned short* __restrict__ Vp) {
  int bid = blockIdx.x;
  int bh = bid >> 6, tt = bid & 63;
  __shared__ unsigned short tile[64 * 72];
  int t = threadIdx.x;
  {
    int row = t >> 2, c0 = (t & 3) * 16;
    const short8* src = (const short8*)(vRM + ((size_t)bh * 4096 + tt * 64 + row) * 64 + c0);
    short8 a0 = src[0], a1 = src[1];
    *(short8*)(tile + row * 72 + c0) = a0;
    *(short8*)(tile + row * 72 + c0 + 8) = a1;
  }
  __syncthreads();
#pragma unroll
  for (int ss = 0; ss < 2; ++ss) {
    int s = ss * 256 + t;
    int p = s >> 6, l = s & 63;
    int d = (p & 1) * 32 + (l & 31);
    int kl = (p >> 2) * 32 + ((p >> 1) & 1) * 16 + (l >> 5) * 8;
    short8 v;
#pragma unroll
    for (int j = 0; j < 8; ++j) v[j] = (short)tile[(kl + j) * 72 + d];
    *(short8*)(Vp + (((size_t)(bh * 64 + tt) * 8 + p) << 9) + l * 8) = v;
  }
}

// ---------------- K6: flash attention v5 (split-k waves, all-dense planes) ---
// 4 waves/block: wq = q-group (32 rows), wk = k-half. Plane-major LDS AND
// plane-major global (Qp/Kp/Vp) -> every DMA reads contiguous 1KB and every
// ds_read_b128 reads contiguous 1KB (conflict-free, R6-verified).
// No max tracking (logits bounded); P redistributed in-register.
__global__ __launch_bounds__(256) void k_attn(const unsigned short* __restrict__ Qp,
                                              const unsigned short* __restrict__ Kp,
                                              const unsigned short* __restrict__ Vp,
                                              unsigned short* __restrict__ att) {
  __shared__ char smem[32768];   // buf0 @0, buf1 @16384
  const int t = threadIdx.x, wave = t >> 6, lane = t & 63;
  const int l31 = lane & 31, lh = lane >> 5;
  const int wq = wave >> 1, wk = wave & 1;
  int bid0 = blockIdx.x;
  int bid = (bid0 & 7) * 128 + (bid0 >> 3);   // XCD swizzle (bijective: 1024 = 8*128)
  int bh = bid >> 6, qt = bid & 63;
  int b = bh >> 3, h = bh & 7;
  const float C = 0.125f * 1.4426950408889634f;   // scale * log2(e)

  const char* kCur = (const char*)Kp + (size_t)bh * 524288;   // 64 tiles * 8KB
  const char* vCur = (const char*)Vp + (size_t)bh * 524288;
  const char* qSrc = (const char*)Qp + (size_t)bh * 524288 + (size_t)qt * 8192;

  // prologue: Q planes -> buf1 (transient), K0/V0 -> buf0
#pragma unroll
  for (int i = 0; i < 2; ++i) {
    int p = i * 4 + wave;
    async16(qSrc + p * 1024 + lane * 16, smem + 16384 + p * 1024);
    async16(kCur + p * 1024 + lane * 16, smem + p * 1024);
    async16(vCur + p * 1024 + lane * 16, smem + 8192 + p * 1024);
  }
  kCur += 8192; vCur += 8192;

  const int rbK = wk * 4096 + lane * 16;
  const int rbV = 8192 + wk * 4096 + lane * 16;
  const int rbQ = 16384 + wq * 4096 + lane * 16;

  __syncthreads();
  short8 qa[4];
#pragma unroll
  for (int kk = 0; kk < 4; ++kk)
    qa[kk] = *(const short8*)(smem + rbQ + kk * 1024);
  __syncthreads();   // Q reads done before iter0 overwrites buf1

  f32x16 o0 = (f32x16)0.f, o1 = (f32x16)0.f;
  float lsum = 0.f;

#define ATTN_BODY(CURB, NXTB)                                                          \
  {                                                                                    \
    _Pragma("unroll")                                                                  \
    for (int i = 0; i < 2; ++i) {                                                      \
      int p = i * 4 + wave;                                                            \
      async16(kCur + p * 1024 + lane * 16, smem + (NXTB) + p * 1024);                  \
      async16(vCur + p * 1024 + lane * 16, smem + (NXTB) + 8192 + p * 1024);           \
    }                                                                                  \
    kCur += 8192; vCur += 8192;                                                        \
    f32x16 sT = (f32x16)0.f;                                                           \
    __builtin_amdgcn_s_setprio(1);                                                     \
    _Pragma("unroll")                                                                  \
    for (int kk = 0; kk < 4; ++kk) {                                                   \
      short8 ka = *(const short8*)(smem + (CURB) + rbK + kk * 1024);                   \
      sT = __builtin_amdgcn_mfma_f32_32x32x16_bf16(ka, qa[kk], sT, 0, 0, 0);           \
    }                                                                                  \
    __builtin_amdgcn_s_setprio(0);                                                     \
    float ls0 = 0.f, ls1 = 0.f;                                                        \
    _Pragma("unroll")                                                                  \
    for (int r = 0; r < 16; r += 2) {                                                  \
      sT[r]     = __builtin_amdgcn_exp2f(sT[r] * C);                                   \
      sT[r + 1] = __builtin_amdgcn_exp2f(sT[r + 1] * C);                               \
      ls0 += sT[r]; ls1 += sT[r + 1];                                                  \
    }                                                                                  \
    lsum += ls0 + ls1;                                                                 \
    __builtin_amdgcn_s_setprio(1);                                                     \
    _Pragma("unroll")                                                                  \
    for (int kc = 0; kc < 2; ++kc) {                                                   \
      int rb = kc * 8;                                                                 \
      unsigned int x0 = cvt_pk_bf16(sT[rb],     sT[rb + 1]);                           \
      unsigned int x1 = cvt_pk_bf16(sT[rb + 2], sT[rb + 3]);                           \
      unsigned int x2 = cvt_pk_bf16(sT[rb + 4], sT[rb + 5]);                           \
      unsigned int x3 = cvt_pk_bf16(sT[rb + 6], sT[rb + 7]);                           \
      unsigned int u0 = x0, u1 = x1, u2 = x2, u3 = x3;                                 \
      asm("v_permlane32_swap_b32 %0, %1" : "+v"(x0), "+v"(u0));                        \
      asm("v_permlane32_swap_b32 %0, %1" : "+v"(x1), "+v"(u1));                        \
      asm("v_permlane32_swap_b32 %0, %1" : "+v"(x2), "+v"(u2));                        \
      asm("v_permlane32_swap_b32 %0, %1" : "+v"(x3), "+v"(u3));                        \
      union { unsigned int d[4]; short8 s; } pb;                                       \
      pb.d[0] = lh ? x2 : x0;                                                          \
      pb.d[1] = lh ? x3 : x1;                                                          \
      pb.d[2] = lh ? u2 : u0;                                                          \
      pb.d[3] = lh ? u3 : u1;                                                          \
      short8 va0 = *(const short8*)(smem + (CURB) + rbV + kc * 2048);                  \
      o0 = __builtin_amdgcn_mfma_f32_32x32x16_bf16(va0, pb.s, o0, 0, 0, 0);            \
      short8 va1 = *(const short8*)(smem + (CURB) + rbV + kc * 2048 + 1024);           \
      o1 = __builtin_amdgcn_mfma_f32_32x32x16_bf16(va1, pb.s, o1, 0, 0, 0);            \
    }                                                                                  \
    __builtin_amdgcn_s_setprio(0);                                                     \
    __syncthreads();                                                                   \
  }

  // 64 kv-tiles; last staged tile reads 8KB past this bh's planes (allocated
  // workspace, never consumed).
  for (int it2 = 0; it2 < 32; ++it2) {
    ATTN_BODY(0, 16384)
    ATTN_BODY(16384, 0)
  }
#undef ATTN_BODY

  // ---- cross-k-half reduce + store ----
  lsum += __shfl_xor(lsum, 32, 64);
  if (wk) {
    char* os = smem + wq * 8192;
#pragma unroll
    for (int dt = 0; dt < 2; ++dt)
#pragma unroll
      for (int rp = 0; rp < 4; ++rp) {
        f32x4 v;
        v[0] = (dt ? o1 : o0)[4 * rp];     v[1] = (dt ? o1 : o0)[4 * rp + 1];
        v[2] = (dt ? o1 : o0)[4 * rp + 2]; v[3] = (dt ? o1 : o0)[4 * rp + 3];
        *(f32x4*)(os + (dt * 4 + rp) * 1024 + lane * 16) = v;
      }
    *(float*)(smem + 16384 + wq * 256 + lane * 4) = lsum;
  }
  __syncthreads();
  if (!wk) {
    float lt = lsum + *(const float*)(smem + 16384 + wq * 256 + lane * 4);
    float rl = 1.f / lt;
    const char* os = smem + wq * 8192;
#pragma unroll
    for (int dt = 0; dt < 2; ++dt)
#pragma unroll
      for (int rp = 0; rp < 4; ++rp) {
        f32x4 v = *(const f32x4*)(os + (dt * 4 + rp) * 1024 + lane * 16);
        if (dt) {
          o1[4 * rp] += v[0]; o1[4 * rp + 1] += v[1];
          o1[4 * rp + 2] += v[2]; o1[4 * rp + 3] += v[3];
        } else {
          o0[4 * rp] += v[0]; o0[4 * rp + 1] += v[1];
          o0[4 * rp + 2] += v[2]; o0[4 * rp + 3] += v[3];
        }
      }
    unsigned short* abase = att + (size_t)(b * NN + qt * 64 + wq * 32 + l31) * CC + h * 64 + 4 * lh;
#pragma unroll
    for (int dt = 0; dt < 2; ++dt)
#pragma unroll
      for (int rp = 0; rp < 8; ++rp) {
        float e0 = (dt ? o1 : o0)[2 * rp], e1 = (dt ? o1 : o0)[2 * rp + 1];
        unsigned int w = cvt_pk_bf16(e0 * rl, e1 * rl);
        *(unsigned int*)(abase + 32 * dt + 8 * (rp >> 1) + 2 * (rp & 1)) = w;
      }
  }
}

// -------- K7: proj GEMM + fused transpose + bias + residual -> d_out --------
__global__ __launch_bounds__(256) void k_projgemm(const unsigned short* __restrict__ att,
                                                  const unsigned short* __restrict__ Wp,
                                                  const float* __restrict__ x,
                                                  const float* __restrict__ bproj,
                                                  float* __restrict__ out) {
  __shared__ char smem[33280];   // 32768 for GEMM tiles; 4*8320 for epilogue staging
  f32x4 acc[4][4];
  int m0 = blockIdx.x * 128, n0 = blockIdx.y * 128;
  gemm_mainloop(att, Wp, smem, m0, n0, acc);
  const int t = threadIdx.x, wave = t >> 6, lane = t & 63;
  const int l15 = lane & 15, lhi = lane >> 4;
  const int wr = wave >> 1, wc = wave & 1;
  __syncthreads();   // all waves done with GEMM tiles
  float* stg = (float*)(smem + wave * 8320);   // per-wave private 32x65 f32
  int b = m0 >> 12;                            // 4096 pixels per batch
  int nbase = (m0 & 4095) + wr * 64;
#pragma unroll
  for (int half = 0; half < 2; ++half) {
#pragma unroll
    for (int nl = 0; nl < 2; ++nl) {
      int ni = half * 2 + nl;
#pragma unroll
      for (int mi = 0; mi < 4; ++mi)
#pragma unroll
        for (int r = 0; r < 4; ++r) {
          int cl = nl * 16 + l15;
          int row = mi * 16 + lhi * 4 + r;
          stg[cl * 65 + row] = acc[mi][ni][r];  // transposed stage
        }
    }
#pragma unroll 4
    for (int i = 0; i < 32; ++i) {
      int oc = n0 + wc * 64 + half * 32 + i;
      float v = stg[i * 65 + lane];
      size_t idx = (size_t)(b * CC + oc) * NN + nbase + lane;
      out[idx] = x[idx] + v + bproj[oc];
    }
    __syncthreads();
  }
}

// ---------------- launch ----------------
extern "C" void kernel_launch(void* const* d_in, const int* in_sizes, int n_in,
                              void* d_out, int out_size, void* d_ws, size_t ws_size,
                              hipStream_t stream) {
  const float* x     = (const float*)d_in[0];
  const float* gw    = (const float*)d_in[1];
  const float* gb    = (const float*)d_in[2];
  const float* wqkv  = (const float*)d_in[3];
  const float* wproj = (const float*)d_in[4];
  const float* bproj = (const float*)d_in[5];
  float* out = (float*)d_out;
  char* ws = (char*)d_ws;

  // workspace layout (bytes); overlays exploit lifetimes:
  //   hTb dead after k_qkvgemm -> Vp reuses it
  //   vRM dead after k_vtransP -> attb reuses it
  unsigned short* Qp     = (unsigned short*)(ws + 0);          // 8388608
  unsigned short* Kp     = (unsigned short*)(ws + 8388608);    // 8388608
  unsigned short* vRM    = (unsigned short*)(ws + 16777216);   // 8388608
  unsigned short* attb   = (unsigned short*)(ws + 16777216);   // overlay (after vtransP)
  unsigned short* hTb    = (unsigned short*)(ws + 25165824);   // 8388608
  unsigned short* Vp     = (unsigned short*)(ws + 25165824);   // overlay (after qkvgemm)
  unsigned short* wqkvb  = (unsigned short*)(ws + 33554432);   // 1572864
  unsigned short* wprojb = (unsigned short*)(ws + 35127296);   // 524288
  float*          stats  = (float*)(ws + 35651584);            // 64*2*4

  k_gnstats<<<64, 256, 0, stream>>>(x, stats);
  k_gnapply<<<1024, 256, 0, stream>>>(x, gw, gb, stats, hTb);
  k_cvt<<<768, 256, 0, stream>>>(wqkv, wqkvb);    // 3*512*512 / 1024
  k_cvt<<<256, 256, 0, stream>>>(wproj, wprojb);  // 512*512 / 1024
  k_qkvgemm<<<dim3(64, 12), 256, 0, stream>>>(hTb, wqkvb, Qp, Kp, vRM);
  k_vtransP<<<1024, 256, 0, stream>>>(vRM, Vp);
  k_attn<<<1024, 256, 0, stream>>>(Qp, Kp, Vp, attb);
  k_projgemm<<<dim3(64, 4), 256, 0, stream>>>(attb, wprojb, x, bproj, out);
}

// Round 8
// 235.764 us; speedup vs baseline: 1.2679x; 1.1078x over previous
//
#include <hip/hip_runtime.h>
#include <math.h>

#define BB 2
#define CC 512
#define NN 4096          // H*W
#define NH 8
#define HD 64
#define NG 32
#define CPG 16           // C / NUM_GROUPS

typedef __attribute__((ext_vector_type(8))) short short8;
typedef __attribute__((ext_vector_type(4))) float f32x4;
typedef __attribute__((ext_vector_type(16))) float f32x16;

typedef __attribute__((address_space(1))) void glb_t;
typedef __attribute__((address_space(3))) void lds_t;

__device__ __forceinline__ void async16(const void* g, void* l) {
  __builtin_amdgcn_global_load_lds((const glb_t*)g, (lds_t*)l, 16, 0, 0);
}

__device__ __forceinline__ unsigned short f2bf(float f) {
  unsigned int u = __float_as_uint(f);
  u += 0x7fffu + ((u >> 16) & 1u);   // RNE
  return (unsigned short)(u >> 16);
}

__device__ __forceinline__ unsigned int cvt_pk_bf16(float a, float b) {
  unsigned int r;
  asm("v_cvt_pk_bf16_f32 %0, %1, %2" : "=v"(r) : "v"(a), "v"(b));
  return r;   // lo = bf16(a), hi = bf16(b)
}

// ------- K1: fused GroupNorm stats (blocks 0..63) + weight f32->bf16 (64..) --
__global__ __launch_bounds__(256) void k_pre(const float* __restrict__ x,
                                             const float* __restrict__ wqkv,
                                             const float* __restrict__ wproj,
                                             float* __restrict__ stats,
                                             unsigned short* __restrict__ wb) {
  int bid = blockIdx.x;
  if (bid >= 64) {   // weight convert: 1,048,576 floats total (wqkv then wproj)
    int i = ((bid - 64) * 256 + threadIdx.x) * 4;
    const float* src = (i < 786432) ? (wqkv + i) : (wproj + (i - 786432));
    float4 v = *(const float4*)src;
    ushort4 o;
    o.x = f2bf(v.x); o.y = f2bf(v.y); o.z = f2bf(v.z); o.w = f2bf(v.w);
    *(ushort4*)(wb + i) = o;
    return;
  }
  int b = bid >> 5, g = bid & 31;
  const float4* p = (const float4*)(x + (size_t)(b * CC + g * CPG) * NN);
  double s = 0.0, sq = 0.0;
  for (int i = threadIdx.x; i < (CPG * NN) / 4; i += 256) {
    float4 v = p[i];
    s  += (double)v.x + (double)v.y + (double)v.z + (double)v.w;
    sq += (double)v.x * v.x + (double)v.y * v.y + (double)v.z * v.z + (double)v.w * v.w;
  }
  __shared__ double red[512];
  red[threadIdx.x] = s; red[256 + threadIdx.x] = sq;
  __syncthreads();
  for (int off = 128; off > 0; off >>= 1) {
    if (threadIdx.x < off) {
      red[threadIdx.x] += red[threadIdx.x + off];
      red[256 + threadIdx.x] += red[256 + threadIdx.x + off];
    }
    __syncthreads();
  }
  if (threadIdx.x == 0) {
    double mean = red[0] / (double)(CPG * NN);
    double var  = red[256] / (double)(CPG * NN) - mean * mean;
    stats[(b * NG + g) * 2]     = (float)mean;
    stats[(b * NG + g) * 2 + 1] = (float)(1.0 / sqrt(var + 1e-5));
  }
}

// ------- K2: GN apply + transpose [B,C,N] -> hT[B*N][C] bf16 (vectorized) ----
__global__ __launch_bounds__(256) void k_gnapply(const float* __restrict__ x,
                                                 const float* __restrict__ gw,
                                                 const float* __restrict__ gb,
                                                 const float* __restrict__ stats,
                                                 unsigned short* __restrict__ hT) {
  int bid = blockIdx.x;
  int b = bid >> 9;
  int c0 = ((bid >> 6) & 7) * 64;
  int n0 = (bid & 63) * 64;
  __shared__ float tile[64 * 68];
  int t = threadIdx.x;
#pragma unroll
  for (int i = 0; i < 4; ++i) {
    int idx = i * 256 + t;
    int c = idx >> 4, n4 = (idx & 15) * 4;
    int cg = c0 + c, g = cg >> 4;
    float mu = stats[(b * NG + g) * 2], rs = stats[(b * NG + g) * 2 + 1];
    float w = gw[cg], bb = gb[cg];
    float4 v = *(const float4*)(x + (size_t)(b * CC + cg) * NN + n0 + n4);
    float* dst = tile + c * 68 + n4;
    dst[0] = (v.x - mu) * rs * w + bb;
    dst[1] = (v.y - mu) * rs * w + bb;
    dst[2] = (v.z - mu) * rs * w + bb;
    dst[3] = (v.w - mu) * rs * w + bb;
  }
  __syncthreads();
#pragma unroll
  for (int i = 0; i < 2; ++i) {
    int idx = i * 256 + t;
    int n = idx >> 3, c8 = (idx & 7) * 8;
    short8 o;
#pragma unroll
    for (int j = 0; j < 8; ++j) o[j] = (short)f2bf(tile[(c8 + j) * 68 + n]);
    *(short8*)(hT + (size_t)(b * NN + n0 + n) * CC + c0 + c8) = o;
  }
}

// ------- shared GEMM mainloop: 128x128 tile, K=512 fixed, A[ld=512], B[N][512]
__device__ __forceinline__ void gemm_mainloop(const unsigned short* __restrict__ A,
                                              const unsigned short* __restrict__ Bm,
                                              char* smem, int m0, int n0,
                                              f32x4 acc[4][4]) {
  const int t = threadIdx.x, wave = t >> 6, lane = t & 63;
  const int l15 = lane & 15, lhi = lane >> 4;
  const int wr = wave >> 1, wc = wave & 1;
  const f32x4 fz = {0.f, 0.f, 0.f, 0.f};
#pragma unroll
  for (int mi = 0; mi < 4; ++mi)
#pragma unroll
    for (int ni = 0; ni < 4; ++ni) acc[mi][ni] = fz;

  for (int kt = 0; kt < 8; ++kt) {
    __syncthreads();
#pragma unroll
    for (int issue = 0; issue < 4; ++issue) {
      int slot = issue * 256 + t;
      int row = slot >> 3, g = slot & 7;
      async16(A + (size_t)(m0 + row) * 512 + kt * 64 + g * 8,
              smem + issue * 4096 + wave * 1024);
      async16(Bm + (size_t)(n0 + row) * 512 + kt * 64 + g * 8,
              smem + 16384 + issue * 4096 + wave * 1024);
    }
    __syncthreads();
#pragma unroll
    for (int kk = 0; kk < 2; ++kk) {
      short8 a[4], bf[4];
#pragma unroll
      for (int mi = 0; mi < 4; ++mi)
        a[mi] = *(const short8*)(smem + (wr * 64 + mi * 16 + l15) * 128 + kk * 64 + lhi * 16);
#pragma unroll
      for (int ni = 0; ni < 4; ++ni)
        bf[ni] = *(const short8*)(smem + 16384 + (wc * 64 + ni * 16 + l15) * 128 + kk * 64 + lhi * 16);
#pragma unroll
      for (int mi = 0; mi < 4; ++mi)
#pragma unroll
        for (int ni = 0; ni < 4; ++ni)
          acc[mi][ni] = __builtin_amdgcn_mfma_f32_16x16x32_bf16(a[mi], bf[ni], acc[mi][ni], 0, 0, 0);
    }
  }
}

// ---- K4: QKV GEMM; epilogue assembles plane-major Qp/Kp/Vp in LDS, then
//      coalesced 16B stores. Q pre-scaled by 0.125*log2(e).
// Q/K plane image (per bh, per 64-pixel tile): plane p = (pn>>5)*4 + (c>>4);
//   short slot = ((c>>3)&1)*256 + (pn&31)*8 + (c&7)
// V plane image: p = (pn>>5)*4 + ((pn>>4)&1)*2 + (c>>5);
//   short slot = ((pn>>3)&1)*256 + (c&31)*8 + (pn&7)      (c = d here)
__global__ __launch_bounds__(256) void k_qkvgemm(const unsigned short* __restrict__ hT,
                                                 const unsigned short* __restrict__ Wq,
                                                 unsigned short* __restrict__ Qp,
                                                 unsigned short* __restrict__ Kp,
                                                 unsigned short* __restrict__ Vp) {
  __shared__ char smem[32768];
  f32x4 acc[4][4];
  int m0 = blockIdx.x * 128, n0 = blockIdx.y * 128;
  gemm_mainloop(hT, Wq, smem, m0, n0, acc);
  const int t = threadIdx.x, wave = t >> 6, lane = t & 63;
  const int l15 = lane & 15, lhi = lane >> 4;
  const int wr = wave >> 1, wc = wave & 1;
  const int type = n0 >> 9;            // 0=Q, 1=K, 2=V
  const int h0 = (n0 >> 6) & 7;        // even head base (2 heads per block)
  __syncthreads();                     // mainloop LDS reads done everywhere
  unsigned short* lim = (unsigned short*)smem;   // 16384 shorts = 32KB image
  const float qs = 0.18033688011112042f;         // 0.125 * log2(e)
#pragma unroll
  for (int mi = 0; mi < 4; ++mi)
#pragma unroll
    for (int ni = 0; ni < 4; ++ni)
#pragma unroll
      for (int r = 0; r < 4; ++r) {
        int pr = wr * 64 + mi * 16 + lhi * 4 + r;   // rel pixel 0..127
        int oc = wc * 64 + ni * 16 + l15;           // rel channel 0..127
        int hh = oc >> 6, c = oc & 63;
        int tt2 = pr >> 6, pn = pr & 63;
        int idx;
        if (type < 2)
          idx = ((hh * 2 + tt2) * 8 + ((pn >> 5) << 2) + (c >> 4)) * 512
              + ((c >> 3) & 1) * 256 + (pn & 31) * 8 + (c & 7);
        else
          idx = ((hh * 2 + tt2) * 8 + ((pn >> 5) << 2) + (((pn >> 4) & 1) << 1) + (c >> 5)) * 512
              + ((pn >> 3) & 1) * 256 + (c & 31) * 8 + (pn & 7);
        float v = acc[mi][ni][r];
        if (type == 0) v *= qs;
        lim[idx] = f2bf(v);
      }
  __syncthreads();
  unsigned short* gbp = type == 0 ? Qp : (type == 1 ? Kp : Vp);
  int b = m0 >> 12, tile0 = (m0 & 4095) >> 6;
#pragma unroll
  for (int i = 0; i < 8; ++i) {
    int cidx = i * 256 + t;            // 2048 chunks of 16B
    int pg = cidx >> 6;                // [hh(2)][tt(2)][p(8)]
    int bh = b * 8 + h0 + (pg >> 4);
    size_t dst = (size_t)bh * 262144 + (size_t)(tile0 + ((pg >> 3) & 1)) * 4096
               + (size_t)(pg & 7) * 512 + (size_t)(cidx & 63) * 8;
    *(short8*)(gbp + dst) = *(const short8*)(lim + cidx * 8);
  }
}

// ---------------- K6: flash attention v6 (plane-major, lean VALU) -----------
// 4 waves/block: wq = q-group (32 rows), wk = k-half. All DMA reads and all
// ds_read_b128 are contiguous 1KB (conflict-free, R6/R7-verified).
// Q pre-scaled -> exp2 directly. P redistribution: 2 permlane32_swap per kc.
__global__ __launch_bounds__(256) void k_attn(const unsigned short* __restrict__ Qp,
                                              const unsigned short* __restrict__ Kp,
                                              const unsigned short* __restrict__ Vp,
                                              unsigned short* __restrict__ att) {
  __shared__ char smem[32768];   // buf0 @0, buf1 @16384
  const int t = threadIdx.x, wave = t >> 6, lane = t & 63;
  const int l31 = lane & 31, lh = lane >> 5;
  const int wq = wave >> 1, wk = wave & 1;
  int bid0 = blockIdx.x;
  int bid = (bid0 & 7) * 128 + (bid0 >> 3);   // XCD swizzle (bijective: 1024 = 8*128)
  int bh = bid >> 6, qt = bid & 63;
  int b = bh >> 3, h = bh & 7;

  const char* kCur = (const char*)Kp + (size_t)bh * 524288;
  const char* vCur = (const char*)Vp + (size_t)bh * 524288;
  const char* qSrc = (const char*)Qp + (size_t)bh * 524288 + (size_t)qt * 8192;

#pragma unroll
  for (int i = 0; i < 2; ++i) {
    int p = i * 4 + wave;
    async16(qSrc + p * 1024 + lane * 16, smem + 16384 + p * 1024);
    async16(kCur + p * 1024 + lane * 16, smem + p * 1024);
    async16(vCur + p * 1024 + lane * 16, smem + 8192 + p * 1024);
  }
  kCur += 8192; vCur += 8192;

  const int rbK = wk * 4096 + lane * 16;
  const int rbV = 8192 + wk * 4096 + lane * 16;
  const int rbQ = 16384 + wq * 4096 + lane * 16;

  __syncthreads();
  short8 qa[4];
#pragma unroll
  for (int kk = 0; kk < 4; ++kk)
    qa[kk] = *(const short8*)(smem + rbQ + kk * 1024);
  __syncthreads();

  f32x16 o0 = (f32x16)0.f, o1 = (f32x16)0.f;
  float lsum = 0.f;

#define ATTN_BODY(CURB, NXTB)                                                          \
  {                                                                                    \
    _Pragma("unroll")                                                                  \
    for (int i = 0; i < 2; ++i) {                                                      \
      int p = i * 4 + wave;                                                            \
      async16(kCur + p * 1024 + lane * 16, smem + (NXTB) + p * 1024);                  \
      async16(vCur + p * 1024 + lane * 16, smem + (NXTB) + 8192 + p * 1024);           \
    }                                                                                  \
    kCur += 8192; vCur += 8192;                                                        \
    f32x16 sT = (f32x16)0.f;                                                           \
    __builtin_amdgcn_s_setprio(1);                                                     \
    _Pragma("unroll")                                                                  \
    for (int kk = 0; kk < 4; ++kk) {                                                   \
      short8 ka = *(const short8*)(smem + (CURB) + rbK + kk * 1024);                   \
      sT = __builtin_amdgcn_mfma_f32_32x32x16_bf16(ka, qa[kk], sT, 0, 0, 0);           \
    }                                                                                  \
    __builtin_amdgcn_s_setprio(0);                                                     \
    float ls0 = 0.f, ls1 = 0.f;                                                        \
    _Pragma("unroll")                                                                  \
    for (int r = 0; r < 16; r += 2) {                                                  \
      sT[r]     = __builtin_amdgcn_exp2f(sT[r]);                                       \
      sT[r + 1] = __builtin_amdgcn_exp2f(sT[r + 1]);                                   \
      ls0 += sT[r]; ls1 += sT[r + 1];                                                  \
    }                                                                                  \
    lsum += ls0 + ls1;                                                                 \
    __builtin_amdgcn_s_setprio(1);                                                     \
    _Pragma("unroll")                                                                  \
    for (int kc = 0; kc < 2; ++kc) {                                                   \
      int rb = kc * 8;                                                                 \
      unsigned int x0 = cvt_pk_bf16(sT[rb],     sT[rb + 1]);                           \
      unsigned int x1 = cvt_pk_bf16(sT[rb + 2], sT[rb + 3]);                           \
      unsigned int x2 = cvt_pk_bf16(sT[rb + 4], sT[rb + 5]);                           \
      unsigned int x3 = cvt_pk_bf16(sT[rb + 6], sT[rb + 7]);                           \
      asm("v_permlane32_swap_b32 %0, %1" : "+v"(x0), "+v"(x2));                        \
      asm("v_permlane32_swap_b32 %0, %1" : "+v"(x1), "+v"(x3));                        \
      union { unsigned int d[4]; short8 s; } pb;                                       \
      pb.d[0] = x0; pb.d[1] = x1; pb.d[2] = x2; pb.d[3] = x3;                          \
      short8 va0 = *(const short8*)(smem + (CURB) + rbV + kc * 2048);                  \
      o0 = __builtin_amdgcn_mfma_f32_32x32x16_bf16(va0, pb.s, o0, 0, 0, 0);            \
      short8 va1 = *(const short8*)(smem + (CURB) + rbV + kc * 2048 + 1024);           \
      o1 = __builtin_amdgcn_mfma_f32_32x32x16_bf16(va1, pb.s, o1, 0, 0, 0);            \
    }                                                                                  \
    __builtin_amdgcn_s_setprio(0);                                                     \
    __syncthreads();                                                                   \
  }

  for (int it2 = 0; it2 < 32; ++it2) {
    ATTN_BODY(0, 16384)
    ATTN_BODY(16384, 0)
  }
#undef ATTN_BODY

  // ---- cross-k-half reduce + store ----
  lsum += __shfl_xor(lsum, 32, 64);
  if (wk) {
    char* os = smem + wq * 8192;
#pragma unroll
    for (int dt = 0; dt < 2; ++dt)
#pragma unroll
      for (int rp = 0; rp < 4; ++rp) {
        f32x4 v;
        v[0] = (dt ? o1 : o0)[4 * rp];     v[1] = (dt ? o1 : o0)[4 * rp + 1];
        v[2] = (dt ? o1 : o0)[4 * rp + 2]; v[3] = (dt ? o1 : o0)[4 * rp + 3];
        *(f32x4*)(os + (dt * 4 + rp) * 1024 + lane * 16) = v;
      }
    *(float*)(smem + 16384 + wq * 256 + lane * 4) = lsum;
  }
  __syncthreads();
  if (!wk) {
    float lt = lsum + *(const float*)(smem + 16384 + wq * 256 + lane * 4);
    float rl = 1.f / lt;
    const char* os = smem + wq * 8192;
#pragma unroll
    for (int dt = 0; dt < 2; ++dt)
#pragma unroll
      for (int rp = 0; rp < 4; ++rp) {
        f32x4 v = *(const f32x4*)(os + (dt * 4 + rp) * 1024 + lane * 16);
        if (dt) {
          o1[4 * rp] += v[0]; o1[4 * rp + 1] += v[1];
          o1[4 * rp + 2] += v[2]; o1[4 * rp + 3] += v[3];
        } else {
          o0[4 * rp] += v[0]; o0[4 * rp + 1] += v[1];
          o0[4 * rp + 2] += v[2]; o0[4 * rp + 3] += v[3];
        }
      }
    unsigned short* abase = att + (size_t)(b * NN + qt * 64 + wq * 32 + l31) * CC + h * 64 + 4 * lh;
#pragma unroll
    for (int dt = 0; dt < 2; ++dt)
#pragma unroll
      for (int rp = 0; rp < 8; ++rp) {
        float e0 = (dt ? o1 : o0)[2 * rp], e1 = (dt ? o1 : o0)[2 * rp + 1];
        unsigned int w = cvt_pk_bf16(e0 * rl, e1 * rl);
        *(unsigned int*)(abase + 32 * dt + 8 * (rp >> 1) + 2 * (rp & 1)) = w;
      }
  }
}

// -------- K7: proj GEMM + fused transpose + bias + residual -> d_out --------
__global__ __launch_bounds__(256) void k_projgemm(const unsigned short* __restrict__ att,
                                                  const unsigned short* __restrict__ Wp,
                                                  const float* __restrict__ x,
                                                  const float* __restrict__ bproj,
                                                  float* __restrict__ out) {
  __shared__ char smem[33280];
  f32x4 acc[4][4];
  int m0 = blockIdx.x * 128, n0 = blockIdx.y * 128;
  gemm_mainloop(att, Wp, smem, m0, n0, acc);
  const int t = threadIdx.x, wave = t >> 6, lane = t & 63;
  const int l15 = lane & 15, lhi = lane >> 4;
  const int wr = wave >> 1, wc = wave & 1;
  __syncthreads();
  float* stg = (float*)(smem + wave * 8320);
  int b = m0 >> 12;
  int nbase = (m0 & 4095) + wr * 64;
#pragma unroll
  for (int half = 0; half < 2; ++half) {
#pragma unroll
    for (int nl = 0; nl < 2; ++nl) {
      int ni = half * 2 + nl;
#pragma unroll
      for (int mi = 0; mi < 4; ++mi)
#pragma unroll
        for (int r = 0; r < 4; ++r) {
          int cl = nl * 16 + l15;
          int row = mi * 16 + lhi * 4 + r;
          stg[cl * 65 + row] = acc[mi][ni][r];
        }
    }
#pragma unroll 4
    for (int i = 0; i < 32; ++i) {
      int oc = n0 + wc * 64 + half * 32 + i;
      float v = stg[i * 65 + lane];
      size_t idx = (size_t)(b * CC + oc) * NN + nbase + lane;
      out[idx] = x[idx] + v + bproj[oc];
    }
    __syncthreads();
  }
}

// ---------------- launch ----------------
extern "C" void kernel_launch(void* const* d_in, const int* in_sizes, int n_in,
                              void* d_out, int out_size, void* d_ws, size_t ws_size,
                              hipStream_t stream) {
  const float* x     = (const float*)d_in[0];
  const float* gw    = (const float*)d_in[1];
  const float* gb    = (const float*)d_in[2];
  const float* wqkv  = (const float*)d_in[3];
  const float* wproj = (const float*)d_in[4];
  const float* bproj = (const float*)d_in[5];
  float* out = (float*)d_out;
  char* ws = (char*)d_ws;

  // workspace layout (bytes); hTb dead after qkvgemm -> attb overlays it
  unsigned short* Qp     = (unsigned short*)(ws + 0);          // 8388608
  unsigned short* Kp     = (unsigned short*)(ws + 8388608);    // 8388608
  unsigned short* Vp     = (unsigned short*)(ws + 16777216);   // 8388608
  unsigned short* hTb    = (unsigned short*)(ws + 25165824);   // 8388608
  unsigned short* attb   = (unsigned short*)(ws + 25165824);   // overlay
  unsigned short* wqkvb  = (unsigned short*)(ws + 33554432);   // 1572864
  unsigned short* wprojb = (unsigned short*)(ws + 35127296);   // 524288 (contig after wqkvb)
  float*          stats  = (float*)(ws + 35651584);            // 64*2*4

  k_pre<<<1088, 256, 0, stream>>>(x, wqkv, wproj, stats, wqkvb);
  k_gnapply<<<1024, 256, 0, stream>>>(x, gw, gb, stats, hTb);
  k_qkvgemm<<<dim3(64, 12), 256, 0, stream>>>(hTb, wqkvb, Qp, Kp, Vp);
  k_attn<<<1024, 256, 0, stream>>>(Qp, Kp, Vp, attb);
  k_projgemm<<<dim3(64, 4), 256, 0, stream>>>(attb, wprojb, x, bproj, out);
}

// Round 9
// 223.977 us; speedup vs baseline: 1.3346x; 1.0526x over previous
//
#include <hip/hip_runtime.h>
#include <math.h>

#define BB 2
#define CC 512
#define NN 4096          // H*W
#define NH 8
#define HD 64
#define NG 32
#define CPG 16           // C / NUM_GROUPS

typedef __attribute__((ext_vector_type(8))) short short8;
typedef __attribute__((ext_vector_type(4))) float f32x4;
typedef __attribute__((ext_vector_type(16))) float f32x16;

typedef __attribute__((address_space(1))) void glb_t;
typedef __attribute__((address_space(3))) void lds_t;

__device__ __forceinline__ void async16(const void* g, void* l) {
  __builtin_amdgcn_global_load_lds((const glb_t*)g, (lds_t*)l, 16, 0, 0);
}

__device__ __forceinline__ unsigned short f2bf(float f) {
  unsigned int u = __float_as_uint(f);
  u += 0x7fffu + ((u >> 16) & 1u);   // RNE
  return (unsigned short)(u >> 16);
}

__device__ __forceinline__ unsigned int cvt_pk_bf16(float a, float b) {
  unsigned int r;
  asm("v_cvt_pk_bf16_f32 %0, %1, %2" : "=v"(r) : "v"(a), "v"(b));
  return r;   // lo = bf16(a), hi = bf16(b)
}

// ------- K1: fused GroupNorm stats (blocks 0..63) + weight f32->bf16 (64..) --
__global__ __launch_bounds__(256) void k_pre(const float* __restrict__ x,
                                             const float* __restrict__ wqkv,
                                             const float* __restrict__ wproj,
                                             float* __restrict__ stats,
                                             unsigned short* __restrict__ wb) {
  int bid = blockIdx.x;
  if (bid >= 64) {
    int i = ((bid - 64) * 256 + threadIdx.x) * 4;
    const float* src = (i < 786432) ? (wqkv + i) : (wproj + (i - 786432));
    float4 v = *(const float4*)src;
    ushort4 o;
    o.x = f2bf(v.x); o.y = f2bf(v.y); o.z = f2bf(v.z); o.w = f2bf(v.w);
    *(ushort4*)(wb + i) = o;
    return;
  }
  int b = bid >> 5, g = bid & 31;
  const float4* p = (const float4*)(x + (size_t)(b * CC + g * CPG) * NN);
  double s = 0.0, sq = 0.0;
  for (int i = threadIdx.x; i < (CPG * NN) / 4; i += 256) {
    float4 v = p[i];
    s  += (double)v.x + (double)v.y + (double)v.z + (double)v.w;
    sq += (double)v.x * v.x + (double)v.y * v.y + (double)v.z * v.z + (double)v.w * v.w;
  }
  __shared__ double red[512];
  red[threadIdx.x] = s; red[256 + threadIdx.x] = sq;
  __syncthreads();
  for (int off = 128; off > 0; off >>= 1) {
    if (threadIdx.x < off) {
      red[threadIdx.x] += red[threadIdx.x + off];
      red[256 + threadIdx.x] += red[256 + threadIdx.x + off];
    }
    __syncthreads();
  }
  if (threadIdx.x == 0) {
    double mean = red[0] / (double)(CPG * NN);
    double var  = red[256] / (double)(CPG * NN) - mean * mean;
    stats[(b * NG + g) * 2]     = (float)mean;
    stats[(b * NG + g) * 2 + 1] = (float)(1.0 / sqrt(var + 1e-5));
  }
}

// ------- K2: GN apply + transpose [B,C,N] -> hT[B*N][C] bf16 (vectorized) ----
__global__ __launch_bounds__(256) void k_gnapply(const float* __restrict__ x,
                                                 const float* __restrict__ gw,
                                                 const float* __restrict__ gb,
                                                 const float* __restrict__ stats,
                                                 unsigned short* __restrict__ hT) {
  int bid = blockIdx.x;
  int b = bid >> 9;
  int c0 = ((bid >> 6) & 7) * 64;
  int n0 = (bid & 63) * 64;
  __shared__ float tile[64 * 68];
  int t = threadIdx.x;
#pragma unroll
  for (int i = 0; i < 4; ++i) {
    int idx = i * 256 + t;
    int c = idx >> 4, n4 = (idx & 15) * 4;
    int cg = c0 + c, g = cg >> 4;
    float mu = stats[(b * NG + g) * 2], rs = stats[(b * NG + g) * 2 + 1];
    float w = gw[cg], bb = gb[cg];
    float4 v = *(const float4*)(x + (size_t)(b * CC + cg) * NN + n0 + n4);
    float* dst = tile + c * 68 + n4;
    dst[0] = (v.x - mu) * rs * w + bb;
    dst[1] = (v.y - mu) * rs * w + bb;
    dst[2] = (v.z - mu) * rs * w + bb;
    dst[3] = (v.w - mu) * rs * w + bb;
  }
  __syncthreads();
#pragma unroll
  for (int i = 0; i < 2; ++i) {
    int idx = i * 256 + t;
    int n = idx >> 3, c8 = (idx & 7) * 8;
    short8 o;
#pragma unroll
    for (int j = 0; j < 8; ++j) o[j] = (short)f2bf(tile[(c8 + j) * 68 + n]);
    *(short8*)(hT + (size_t)(b * NN + n0 + n) * CC + c0 + c8) = o;
  }
}

// ------- shared GEMM mainloop: 128x128 tile, K=512 fixed, A[ld=512], B[N][512]
__device__ __forceinline__ void gemm_mainloop(const unsigned short* __restrict__ A,
                                              const unsigned short* __restrict__ Bm,
                                              char* smem, int m0, int n0,
                                              f32x4 acc[4][4]) {
  const int t = threadIdx.x, wave = t >> 6, lane = t & 63;
  const int l15 = lane & 15, lhi = lane >> 4;
  const int wr = wave >> 1, wc = wave & 1;
  const f32x4 fz = {0.f, 0.f, 0.f, 0.f};
#pragma unroll
  for (int mi = 0; mi < 4; ++mi)
#pragma unroll
    for (int ni = 0; ni < 4; ++ni) acc[mi][ni] = fz;

  for (int kt = 0; kt < 8; ++kt) {
    __syncthreads();
#pragma unroll
    for (int issue = 0; issue < 4; ++issue) {
      int slot = issue * 256 + t;
      int row = slot >> 3, g = slot & 7;
      async16(A + (size_t)(m0 + row) * 512 + kt * 64 + g * 8,
              smem + issue * 4096 + wave * 1024);
      async16(Bm + (size_t)(n0 + row) * 512 + kt * 64 + g * 8,
              smem + 16384 + issue * 4096 + wave * 1024);
    }
    __syncthreads();
#pragma unroll
    for (int kk = 0; kk < 2; ++kk) {
      short8 a[4], bf[4];
#pragma unroll
      for (int mi = 0; mi < 4; ++mi)
        a[mi] = *(const short8*)(smem + (wr * 64 + mi * 16 + l15) * 128 + kk * 64 + lhi * 16);
#pragma unroll
      for (int ni = 0; ni < 4; ++ni)
        bf[ni] = *(const short8*)(smem + 16384 + (wc * 64 + ni * 16 + l15) * 128 + kk * 64 + lhi * 16);
#pragma unroll
      for (int mi = 0; mi < 4; ++mi)
#pragma unroll
        for (int ni = 0; ni < 4; ++ni)
          acc[mi][ni] = __builtin_amdgcn_mfma_f32_16x16x32_bf16(a[mi], bf[ni], acc[mi][ni], 0, 0, 0);
    }
  }
}

// ---- K4: QKV GEMM; epilogue assembles plane-major Qp/Kp/Vp in LDS, then
//      coalesced 16B stores. Q pre-scaled by 0.125*log2(e).
__global__ __launch_bounds__(256) void k_qkvgemm(const unsigned short* __restrict__ hT,
                                                 const unsigned short* __restrict__ Wq,
                                                 unsigned short* __restrict__ Qp,
                                                 unsigned short* __restrict__ Kp,
                                                 unsigned short* __restrict__ Vp) {
  __shared__ char smem[32768];
  f32x4 acc[4][4];
  int m0 = blockIdx.x * 128, n0 = blockIdx.y * 128;
  gemm_mainloop(hT, Wq, smem, m0, n0, acc);
  const int t = threadIdx.x, wave = t >> 6, lane = t & 63;
  const int l15 = lane & 15, lhi = lane >> 4;
  const int wr = wave >> 1, wc = wave & 1;
  const int type = n0 >> 9;            // 0=Q, 1=K, 2=V
  const int h0 = (n0 >> 6) & 7;
  __syncthreads();
  unsigned short* lim = (unsigned short*)smem;
  const float qs = 0.18033688011112042f;         // 0.125 * log2(e)
#pragma unroll
  for (int mi = 0; mi < 4; ++mi)
#pragma unroll
    for (int ni = 0; ni < 4; ++ni)
#pragma unroll
      for (int r = 0; r < 4; ++r) {
        int pr = wr * 64 + mi * 16 + lhi * 4 + r;
        int oc = wc * 64 + ni * 16 + l15;
        int hh = oc >> 6, c = oc & 63;
        int tt2 = pr >> 6, pn = pr & 63;
        int idx;
        if (type < 2)
          idx = ((hh * 2 + tt2) * 8 + ((pn >> 5) << 2) + (c >> 4)) * 512
              + ((c >> 3) & 1) * 256 + (pn & 31) * 8 + (c & 7);
        else
          idx = ((hh * 2 + tt2) * 8 + ((pn >> 5) << 2) + (((pn >> 4) & 1) << 1) + (c >> 5)) * 512
              + ((pn >> 3) & 1) * 256 + (c & 31) * 8 + (pn & 7);
        float v = acc[mi][ni][r];
        if (type == 0) v *= qs;
        lim[idx] = f2bf(v);
      }
  __syncthreads();
  unsigned short* gbp = type == 0 ? Qp : (type == 1 ? Kp : Vp);
  int b = m0 >> 12, tile0 = (m0 & 4095) >> 6;
#pragma unroll
  for (int i = 0; i < 8; ++i) {
    int cidx = i * 256 + t;
    int pg = cidx >> 6;
    int bh = b * 8 + h0 + (pg >> 4);
    size_t dst = (size_t)bh * 262144 + (size_t)(tile0 + ((pg >> 3) & 1)) * 4096
               + (size_t)(pg & 7) * 512 + (size_t)(cidx & 63) * 8;
    *(short8*)(gbp + dst) = *(const short8*)(lim + cidx * 8);
  }
}

// ---------------- K6: flash attention v7 — barrier-free wave-private pipeline
// 512 blocks x 4 waves. Wave = (qw: 64-q tile half of block) x (wk: 32-k half).
// Each wave stages ITS OWN K-half+V-half planes (8KB/tile) into private LDS
// (16KB dbuf); NO __syncthreads in the loop — counted s_waitcnt vmcnt(8) only.
// 2 q-groups per wave reuse each ka/va read (16 MFMA : 8 ds_read per tile).
// Final cross-wk O/l reduce via LDS with the kernel's only barriers.
__global__ __launch_bounds__(256, 2) void k_attn(const unsigned short* __restrict__ Qp,
                                                 const unsigned short* __restrict__ Kp,
                                                 const unsigned short* __restrict__ Vp,
                                                 unsigned short* __restrict__ att) {
  __shared__ char smem[69632];   // 4 waves * 16KB private + 2KB lsum scratch
  const int t = threadIdx.x, wave = t >> 6, lane = t & 63;
  const int l31 = lane & 31, lh = lane >> 5;
  const int qw = wave >> 1, wk = wave & 1;
  int bid0 = blockIdx.x;
  // XCD-bijective map: XCD j owns bh {2j, 2j+1}  (512 = 8 XCD * 64)
  int xcd = bid0 & 7, rr = bid0 >> 3;
  int bh = xcd * 2 + (rr >> 5), qp = rr & 31;
  int qt = qp * 2 + qw;                 // 64-q tile 0..63
  int b = bh >> 3, h = bh & 7;

  char* myLds = smem + wave * 16384;    // buf0 @0 (K 0..4K, V 4K..8K), buf1 @8192
  const char* kPtr = (const char*)Kp + (size_t)bh * 524288 + wk * 4096 + lane * 16;
  const char* vPtr = (const char*)Vp + (size_t)bh * 524288 + wk * 4096 + lane * 16;
  const char* qPtr = (const char*)Qp + (size_t)bh * 524288 + (size_t)qt * 8192 + lane * 16;

  // ---- prologue: Q (8 planes) -> buf1 region; K0/V0 -> buf0. Wave-private. --
#pragma unroll
  for (int j = 0; j < 4; ++j) {
    async16(qPtr + j * 1024, myLds + 8192 + j * 1024);
    async16(qPtr + 4096 + j * 1024, myLds + 12288 + j * 1024);
  }
#pragma unroll
  for (int j = 0; j < 4; ++j) {
    async16(kPtr + j * 1024, myLds + j * 1024);
    async16(vPtr + j * 1024, myLds + 4096 + j * 1024);
  }
  kPtr += 8192; vPtr += 8192;
  asm volatile("s_waitcnt vmcnt(8)" ::: "memory");   // Q's 8 loads done
  __builtin_amdgcn_sched_barrier(0);
  short8 qaA[4], qaB[4];
#pragma unroll
  for (int kk = 0; kk < 4; ++kk) {
    qaA[kk] = *(const short8*)(myLds + 8192 + kk * 1024 + lane * 16);
    qaB[kk] = *(const short8*)(myLds + 12288 + kk * 1024 + lane * 16);
  }
  asm volatile("s_waitcnt lgkmcnt(0)" ::: "memory"); // qa in regs before buf1 reuse
  __builtin_amdgcn_sched_barrier(0);

  const f32x16 fz = (f32x16)0.f;
  f32x16 oA0 = fz, oA1 = fz, oB0 = fz, oB1 = fz;
  float lsA = 0.f, lsB = 0.f;

#define BODY(CURB, NXTB)                                                               \
  {                                                                                    \
    asm volatile("s_waitcnt lgkmcnt(0)" ::: "memory");  /* my reads of NXTB done */    \
    __builtin_amdgcn_sched_barrier(0);                                                 \
    _Pragma("unroll")                                                                  \
    for (int j = 0; j < 4; ++j) {                                                      \
      async16(kPtr + j * 1024, myLds + (NXTB) + j * 1024);                             \
      async16(vPtr + j * 1024, myLds + (NXTB) + 4096 + j * 1024);                      \
    }                                                                                  \
    kPtr += 8192; vPtr += 8192;                                                        \
    asm volatile("s_waitcnt vmcnt(8)" ::: "memory");    /* prev tile's loads done */   \
    __builtin_amdgcn_sched_barrier(0);                                                 \
    f32x16 sA, sB;                                                                     \
    __builtin_amdgcn_s_setprio(1);                                                     \
    {                                                                                  \
      short8 ka = *(const short8*)(myLds + (CURB) + lane * 16);                        \
      sA = __builtin_amdgcn_mfma_f32_32x32x16_bf16(ka, qaA[0], fz, 0, 0, 0);           \
      sB = __builtin_amdgcn_mfma_f32_32x32x16_bf16(ka, qaB[0], fz, 0, 0, 0);           \
      ka = *(const short8*)(myLds + (CURB) + 1024 + lane * 16);                        \
      sA = __builtin_amdgcn_mfma_f32_32x32x16_bf16(ka, qaA[1], sA, 0, 0, 0);           \
      sB = __builtin_amdgcn_mfma_f32_32x32x16_bf16(ka, qaB[1], sB, 0, 0, 0);           \
      ka = *(const short8*)(myLds + (CURB) + 2048 + lane * 16);                        \
      sA = __builtin_amdgcn_mfma_f32_32x32x16_bf16(ka, qaA[2], sA, 0, 0, 0);           \
      sB = __builtin_amdgcn_mfma_f32_32x32x16_bf16(ka, qaB[2], sB, 0, 0, 0);           \
      ka = *(const short8*)(myLds + (CURB) + 3072 + lane * 16);                        \
      sA = __builtin_amdgcn_mfma_f32_32x32x16_bf16(ka, qaA[3], sA, 0, 0, 0);           \
      sB = __builtin_amdgcn_mfma_f32_32x32x16_bf16(ka, qaB[3], sB, 0, 0, 0);           \
    }                                                                                  \
    __builtin_amdgcn_s_setprio(0);                                                     \
    short8 va0 = *(const short8*)(myLds + (CURB) + 4096 + lane * 16);                  \
    short8 va1 = *(const short8*)(myLds + (CURB) + 5120 + lane * 16);                  \
    short8 va2 = *(const short8*)(myLds + (CURB) + 6144 + lane * 16);                  \
    short8 va3 = *(const short8*)(myLds + (CURB) + 7168 + lane * 16);                  \
    float g0 = 0.f, g1 = 0.f;                                                          \
    _Pragma("unroll")                                                                  \
    for (int r = 0; r < 16; r += 2) {                                                  \
      sA[r]     = __builtin_amdgcn_exp2f(sA[r]);                                       \
      sA[r + 1] = __builtin_amdgcn_exp2f(sA[r + 1]);                                   \
      g0 += sA[r]; g1 += sA[r + 1];                                                    \
    }                                                                                  \
    lsA += g0 + g1;                                                                    \
    __builtin_amdgcn_s_setprio(1);                                                     \
    _Pragma("unroll")                                                                  \
    for (int kc = 0; kc < 2; ++kc) {                                                   \
      int rb = kc * 8;                                                                 \
      unsigned int x0 = cvt_pk_bf16(sA[rb],     sA[rb + 1]);                           \
      unsigned int x1 = cvt_pk_bf16(sA[rb + 2], sA[rb + 3]);                           \
      unsigned int x2 = cvt_pk_bf16(sA[rb + 4], sA[rb + 5]);                           \
      unsigned int x3 = cvt_pk_bf16(sA[rb + 6], sA[rb + 7]);                           \
      asm("v_permlane32_swap_b32 %0, %1" : "+v"(x0), "+v"(x2));                        \
      asm("v_permlane32_swap_b32 %0, %1" : "+v"(x1), "+v"(x3));                        \
      union { unsigned int d[4]; short8 s; } pb;                                       \
      pb.d[0] = x0; pb.d[1] = x1; pb.d[2] = x2; pb.d[3] = x3;                          \
      oA0 = __builtin_amdgcn_mfma_f32_32x32x16_bf16(kc ? va2 : va0, pb.s, oA0, 0, 0, 0); \
      oA1 = __builtin_amdgcn_mfma_f32_32x32x16_bf16(kc ? va3 : va1, pb.s, oA1, 0, 0, 0); \
    }                                                                                  \
    __builtin_amdgcn_s_setprio(0);                                                     \
    g0 = 0.f; g1 = 0.f;                                                                \
    _Pragma("unroll")                                                                  \
    for (int r = 0; r < 16; r += 2) {                                                  \
      sB[r]     = __builtin_amdgcn_exp2f(sB[r]);                                       \
      sB[r + 1] = __builtin_amdgcn_exp2f(sB[r + 1]);                                   \
      g0 += sB[r]; g1 += sB[r + 1];                                                    \
    }                                                                                  \
    lsB += g0 + g1;                                                                    \
    __builtin_amdgcn_s_setprio(1);                                                     \
    _Pragma("unroll")                                                                  \
    for (int kc = 0; kc < 2; ++kc) {                                                   \
      int rb = kc * 8;                                                                 \
      unsigned int x0 = cvt_pk_bf16(sB[rb],     sB[rb + 1]);                           \
      unsigned int x1 = cvt_pk_bf16(sB[rb + 2], sB[rb + 3]);                           \
      unsigned int x2 = cvt_pk_bf16(sB[rb + 4], sB[rb + 5]);                           \
      unsigned int x3 = cvt_pk_bf16(sB[rb + 6], sB[rb + 7]);                           \
      asm("v_permlane32_swap_b32 %0, %1" : "+v"(x0), "+v"(x2));                        \
      asm("v_permlane32_swap_b32 %0, %1" : "+v"(x1), "+v"(x3));                        \
      union { unsigned int d[4]; short8 s; } pb;                                       \
      pb.d[0] = x0; pb.d[1] = x1; pb.d[2] = x2; pb.d[3] = x3;                          \
      oB0 = __builtin_amdgcn_mfma_f32_32x32x16_bf16(kc ? va2 : va0, pb.s, oB0, 0, 0, 0); \
      oB1 = __builtin_amdgcn_mfma_f32_32x32x16_bf16(kc ? va3 : va1, pb.s, oB1, 0, 0, 0); \
    }                                                                                  \
    __builtin_amdgcn_s_setprio(0);                                                     \
  }

  for (int it2 = 0; it2 < 32; ++it2) {
    BODY(0, 8192)
    BODY(8192, 0)
  }
#undef BODY

  // ---- cross-wk reduce (only barriers in the kernel; they also drain the
  //      final dead prefetch's DMA before partials overwrite the buffers) ----
  lsA += __shfl_xor(lsA, 32, 64);
  lsB += __shfl_xor(lsB, 32, 64);
  __syncthreads();
  if (wk) {
#pragma unroll
    for (int c = 0; c < 4; ++c) {
      f32x4 w;
      w[0] = oA0[4 * c]; w[1] = oA0[4 * c + 1]; w[2] = oA0[4 * c + 2]; w[3] = oA0[4 * c + 3];
      *(f32x4*)(myLds + c * 1024 + lane * 16) = w;
      w[0] = oA1[4 * c]; w[1] = oA1[4 * c + 1]; w[2] = oA1[4 * c + 2]; w[3] = oA1[4 * c + 3];
      *(f32x4*)(myLds + 4096 + c * 1024 + lane * 16) = w;
      w[0] = oB0[4 * c]; w[1] = oB0[4 * c + 1]; w[2] = oB0[4 * c + 2]; w[3] = oB0[4 * c + 3];
      *(f32x4*)(myLds + 8192 + c * 1024 + lane * 16) = w;
      w[0] = oB1[4 * c]; w[1] = oB1[4 * c + 1]; w[2] = oB1[4 * c + 2]; w[3] = oB1[4 * c + 3];
      *(f32x4*)(myLds + 12288 + c * 1024 + lane * 16) = w;
    }
    float2 lp; lp.x = lsA; lp.y = lsB;
    *(float2*)(smem + 65536 + wave * 512 + lane * 8) = lp;
  }
  __syncthreads();
  if (!wk) {
    const char* ps = myLds + 16384;    // partner (wave+1) area
#pragma unroll
    for (int c = 0; c < 4; ++c) {
      f32x4 v0 = *(const f32x4*)(ps + c * 1024 + lane * 16);
      f32x4 v1 = *(const f32x4*)(ps + 4096 + c * 1024 + lane * 16);
      f32x4 v2 = *(const f32x4*)(ps + 8192 + c * 1024 + lane * 16);
      f32x4 v3 = *(const f32x4*)(ps + 12288 + c * 1024 + lane * 16);
#pragma unroll
      for (int i = 0; i < 4; ++i) {
        oA0[4 * c + i] += v0[i];
        oA1[4 * c + i] += v1[i];
        oB0[4 * c + i] += v2[i];
        oB1[4 * c + i] += v3[i];
      }
    }
    float2 lp = *(const float2*)(smem + 65536 + (wave + 1) * 512 + lane * 8);
    float rlA = 1.f / (lsA + lp.x);
    float rlB = 1.f / (lsB + lp.y);
    unsigned short* aA = att + (size_t)(b * NN + qt * 64 + l31) * CC + h * 64 + 4 * lh;
    unsigned short* aB = att + (size_t)(b * NN + qt * 64 + 32 + l31) * CC + h * 64 + 4 * lh;
#pragma unroll
    for (int rp = 0; rp < 8; ++rp) {
      int off = 8 * (rp >> 1) + 2 * (rp & 1);
      *(unsigned int*)(aA + off)      = cvt_pk_bf16(oA0[2 * rp] * rlA, oA0[2 * rp + 1] * rlA);
      *(unsigned int*)(aA + 32 + off) = cvt_pk_bf16(oA1[2 * rp] * rlA, oA1[2 * rp + 1] * rlA);
      *(unsigned int*)(aB + off)      = cvt_pk_bf16(oB0[2 * rp] * rlB, oB0[2 * rp + 1] * rlB);
      *(unsigned int*)(aB + 32 + off) = cvt_pk_bf16(oB1[2 * rp] * rlB, oB1[2 * rp + 1] * rlB);
    }
  }
}

// -------- K7: proj GEMM + fused transpose + bias + residual -> d_out --------
__global__ __launch_bounds__(256) void k_projgemm(const unsigned short* __restrict__ att,
                                                  const unsigned short* __restrict__ Wp,
                                                  const float* __restrict__ x,
                                                  const float* __restrict__ bproj,
                                                  float* __restrict__ out) {
  __shared__ char smem[33280];
  f32x4 acc[4][4];
  int m0 = blockIdx.x * 128, n0 = blockIdx.y * 128;
  gemm_mainloop(att, Wp, smem, m0, n0, acc);
  const int t = threadIdx.x, wave = t >> 6, lane = t & 63;
  const int l15 = lane & 15, lhi = lane >> 4;
  const int wr = wave >> 1, wc = wave & 1;
  __syncthreads();
  float* stg = (float*)(smem + wave * 8320);
  int b = m0 >> 12;
  int nbase = (m0 & 4095) + wr * 64;
#pragma unroll
  for (int half = 0; half < 2; ++half) {
#pragma unroll
    for (int nl = 0; nl < 2; ++nl) {
      int ni = half * 2 + nl;
#pragma unroll
      for (int mi = 0; mi < 4; ++mi)
#pragma unroll
        for (int r = 0; r < 4; ++r) {
          int cl = nl * 16 + l15;
          int row = mi * 16 + lhi * 4 + r;
          stg[cl * 65 + row] = acc[mi][ni][r];
        }
    }
#pragma unroll 4
    for (int i = 0; i < 32; ++i) {
      int oc = n0 + wc * 64 + half * 32 + i;
      float v = stg[i * 65 + lane];
      size_t idx = (size_t)(b * CC + oc) * NN + nbase + lane;
      out[idx] = x[idx] + v + bproj[oc];
    }
    __syncthreads();
  }
}

// ---------------- launch ----------------
extern "C" void kernel_launch(void* const* d_in, const int* in_sizes, int n_in,
                              void* d_out, int out_size, void* d_ws, size_t ws_size,
                              hipStream_t stream) {
  const float* x     = (const float*)d_in[0];
  const float* gw    = (const float*)d_in[1];
  const float* gb    = (const float*)d_in[2];
  const float* wqkv  = (const float*)d_in[3];
  const float* wproj = (const float*)d_in[4];
  const float* bproj = (const float*)d_in[5];
  float* out = (float*)d_out;
  char* ws = (char*)d_ws;

  unsigned short* Qp     = (unsigned short*)(ws + 0);          // 8388608
  unsigned short* Kp     = (unsigned short*)(ws + 8388608);    // 8388608
  unsigned short* Vp     = (unsigned short*)(ws + 16777216);   // 8388608
  unsigned short* hTb    = (unsigned short*)(ws + 25165824);   // 8388608
  unsigned short* attb   = (unsigned short*)(ws + 25165824);   // overlay
  unsigned short* wqkvb  = (unsigned short*)(ws + 33554432);   // 1572864
  unsigned short* wprojb = (unsigned short*)(ws + 35127296);   // 524288
  float*          stats  = (float*)(ws + 35651584);            // 64*2*4

  k_pre<<<1088, 256, 0, stream>>>(x, wqkv, wproj, stats, wqkvb);
  k_gnapply<<<1024, 256, 0, stream>>>(x, gw, gb, stats, hTb);
  k_qkvgemm<<<dim3(64, 12), 256, 0, stream>>>(hTb, wqkvb, Qp, Kp, Vp);
  k_attn<<<512, 256, 0, stream>>>(Qp, Kp, Vp, attb);
  k_projgemm<<<dim3(64, 4), 256, 0, stream>>>(attb, wprojb, x, bproj, out);
}